// Round 26
// baseline (505.511 us; speedup 1.0000x reference)
//
#include <hip/hip_runtime.h>
#include <cstdint>
#include <cstddef>

typedef __bf16 bf16x8 __attribute__((ext_vector_type(8)));
typedef float  f32x4  __attribute__((ext_vector_type(4)));
typedef unsigned short u16;

#define SCALE_F 0.08838834764831845f
#define QSCALE_F (0.08838834764831845f * 1.4426950408889634f)  // SCALE * log2(e)

__device__ __forceinline__ u16 f2bf(float f) {
  unsigned int u = __builtin_bit_cast(unsigned int, f);
  u += 0x7fffu + ((u >> 16) & 1u);
  return (u16)(u >> 16);
}

__device__ __forceinline__ float b2f(u16 v) {
  unsigned u = (unsigned)v << 16;
  return __builtin_bit_cast(float, u);
}

__device__ __forceinline__ unsigned cvt_pk_bf16(float lo, float hi) {
  unsigned r;
  asm("v_cvt_pk_bf16_f32 %0, %1, %2" : "=v"(r) : "v"(lo), "v"(hi));
  return r;
}

__device__ __forceinline__ void load_lds16(const void* g, void* l) {
  __builtin_amdgcn_global_load_lds((const __attribute__((address_space(1))) void*)g,
                                   (__attribute__((address_space(3))) void*)l,
                                   16, 0, 0);
}

// ------------- fused prep: x cast + weight transposes (64x32 tiles) ----------
__global__ __launch_bounds__(256) void prep_all(const float* __restrict__ x,
                                                const float* __restrict__ wq,
                                                const float* __restrict__ wk,
                                                const float* __restrict__ wv,
                                                const float* __restrict__ wo,
                                                u16* __restrict__ xb,
                                                u16* __restrict__ wqT,
                                                u16* __restrict__ wkvT,
                                                u16* __restrict__ woT) {
  __shared__ float tile[64][33];
  const int tid = threadIdx.x;
  int blk = blockIdx.x;
  if (blk < 2048) {
    int idx = blk * 256 + tid;
    const int n4 = 4096 * 4096 / 4;
    for (; idx < n4; idx += 2048 * 256) {
      float4 v = ((const float4*)x)[idx];
      uint2 pk;
      pk.x = (unsigned)f2bf(v.x) | ((unsigned)f2bf(v.y) << 16);
      pk.y = (unsigned)f2bf(v.z) | ((unsigned)f2bf(v.w) << 16);
      ((uint2*)xb)[idx] = pk;
    }
    return;
  }
  blk -= 2048;
  const float* in; u16* out; long C; int nbx; float scale;
  if (blk < 8192)       { in = wq; out = wqT;                           C = 4096; nbx = 128; scale = QSCALE_F; }
  else if (blk < 10240) { blk -= 8192;  in = wk; out = wkvT;                          C = 1024; nbx = 32; scale = 1.f; }
  else if (blk < 12288) { blk -= 10240; in = wv; out = wkvT + (size_t)1024 * 4096;    C = 1024; nbx = 32; scale = 1.f; }
  else                  { blk -= 12288; in = wo; out = woT;                           C = 4096; nbx = 128; scale = 1.f; }
  const long R = 4096;
  const long c0 = (long)(blk % nbx) * 32, r0 = (long)(blk / nbx) * 64;
  {
    const int tx = tid & 31, ty = tid >> 5;
#pragma unroll
    for (int i = 0; i < 8; i++)
      tile[ty + i * 8][tx] = in[(r0 + ty + i * 8) * C + c0 + tx];
  }
  __syncthreads();
  {
    const int tx = tid & 31, cy = tid >> 5;
#pragma unroll
    for (int i = 0; i < 4; i++) {
      int col = cy + i * 8;
      unsigned val = (unsigned)f2bf(tile[2 * tx][col] * scale) |
                     ((unsigned)f2bf(tile[2 * tx + 1][col] * scale) << 16);
      *(unsigned*)&out[(c0 + col) * R + r0 + 2 * tx] = val;
    }
  }
}

// ---- fused split-K reduce + V transpose over bf16 partials ------------------
__global__ __launch_bounds__(256) void reduce_tr(const u16* __restrict__ part,
                                                 u16* __restrict__ kvb,
                                                 u16* __restrict__ vT) {
  __shared__ u16 tile[64][33];
  const u16* p0 = part;
  const u16* p1 = part + (size_t)4096 * 2048;
  const int tx = threadIdx.x & 31, ty = threadIdx.x >> 5;
  const long c0 = (long)blockIdx.x * 64;   // 0..2047 step 64
  const long r0 = (long)blockIdx.y * 32;
  if (c0 < 1024) {
#pragma unroll
    for (int i = 0; i < 4; i++) {
      const long r = r0 + ty + i * 8;
      unsigned a = *(const unsigned*)&p0[r * 2048 + c0 + 2 * tx];
      unsigned b = *(const unsigned*)&p1[r * 2048 + c0 + 2 * tx];
      unsigned v = (unsigned)f2bf(b2f((u16)a) + b2f((u16)b)) |
                   ((unsigned)f2bf(b2f((u16)(a >> 16)) + b2f((u16)(b >> 16))) << 16);
      *(unsigned*)&kvb[r * 2048 + c0 + 2 * tx] = v;
    }
  } else {
#pragma unroll
    for (int i = 0; i < 4; i++) {
      const long r = r0 + ty + i * 8;
      unsigned a = *(const unsigned*)&p0[r * 2048 + c0 + 2 * tx];
      unsigned b = *(const unsigned*)&p1[r * 2048 + c0 + 2 * tx];
      tile[2 * tx][ty + i * 8]     = f2bf(b2f((u16)a) + b2f((u16)b));
      tile[2 * tx + 1][ty + i * 8] = f2bf(b2f((u16)(a >> 16)) + b2f((u16)(b >> 16)));
    }
    __syncthreads();
    const long d0 = c0 - 1024;
#pragma unroll
    for (int i = 0; i < 8; i++)
      vT[(d0 + ty + i * 8) * 4096 + r0 + tx] = tile[ty + i * 8][tx];
  }
}

// ------------- 256x256 8-phase bf16 GEMM core (R9 de-walled schedule) --------
#define STGA(db, ks, KC) { int kc_ = (KC) < K ? (KC) : 0; \
    load_lds16(gA0 + kc_, &SA[db][ks][s0 * 8]); \
    load_lds16(gA1 + kc_, &SA[db][ks][s1 * 8]); }
#define STGB(db, ks, KC) { int kc_ = (KC) < K ? (KC) : 0; \
    load_lds16(gB0 + kc_, &SB[db][ks][s0 * 8]); \
    load_lds16(gB1 + kc_, &SB[db][ks][s1 * 8]); }

#define PH(MBc, AU, BU, DBn, KSn, MBn, AN, RDB, BN_, STG, DOVM) { \
    STG; \
    if (DOVM) asm volatile("s_waitcnt vmcnt(8)"); \
    __builtin_amdgcn_s_barrier(); \
    _Pragma("unroll") for (int mm = 0; mm < 4; mm++) \
      AN[mm] = *(const bf16x8*)(&SA[DBn][KSn][aoff + (MBn + mm) * 512]); \
    if (RDB) { \
      _Pragma("unroll") for (int n = 0; n < 4; n++) \
        BN_[n] = *(const bf16x8*)(&SB[DBn][KSn][boff + n * 512]); \
    } \
    __builtin_amdgcn_s_setprio(1); \
    _Pragma("unroll") for (int mm = 0; mm < 4; mm++) \
      _Pragma("unroll") for (int n = 0; n < 4; n++) \
        acc[MBc + mm][n] = __builtin_amdgcn_mfma_f32_16x16x32_bf16(AU[mm], BU[n], acc[MBc + mm][n], 0, 0, 0); \
    __builtin_amdgcn_s_setprio(0); \
  }

template <int BF16_OUT>
__device__ __forceinline__ void gemm_core(const u16* __restrict__ A,
                                          const u16* __restrict__ Bt,
                                          void* __restrict__ Cv,
                                          long bm, long bn,
                                          int N, int K, int lda, int ldb) {
  __shared__ u16 SA[2][2][8192];
  __shared__ u16 SB[2][2][8192];
  const int tid = threadIdx.x;
  const int lane = tid & 63;
  const int g = lane >> 4, r16 = lane & 15;
  const int wid = tid >> 6;
  const int wm = wid >> 2, wn = wid & 3;

  const int s0 = tid, s1 = 512 + tid;
  const int rp0 = s0 >> 3, ci0 = (s0 & 7) ^ (rp0 & 7);
  const int rp1 = s1 >> 3, ci1 = (s1 & 7) ^ (rp1 & 7);
  const long gr0 = rp0 * 2 + (ci0 >> 2), gc0 = (ci0 & 3) * 8;
  const long gr1 = rp1 * 2 + (ci1 >> 2), gc1 = (ci1 & 3) * 8;
  const u16* gA0 = A + (bm + gr0) * lda + gc0;
  const u16* gA1 = A + (bm + gr1) * lda + gc1;
  const u16* gB0 = Bt + (bn + gr0) * ldb + gc0;
  const u16* gB1 = Bt + (bn + gr1) * ldb + gc1;

  const int rA = wm * 128 + r16;
  const int aoff = (rA >> 1) * 64 + ((((rA & 1) << 2) + g) ^ ((rA >> 1) & 7)) * 8;
  const int rB = wn * 64 + r16;
  const int boff = (rB >> 1) * 64 + ((((rB & 1) << 2) + g) ^ ((rB >> 1) & 7)) * 8;

  f32x4 acc[8][4];
#pragma unroll
  for (int m = 0; m < 8; m++)
#pragma unroll
    for (int n = 0; n < 4; n++)
#pragma unroll
      for (int j = 0; j < 4; j++) acc[m][n][j] = 0.f;

  bf16x8 afrX[4], afrY[4], bfrX[4], bfrY[4];

  STGA(0, 0, 0); STGB(0, 0, 0);
  STGA(0, 1, 32); STGB(0, 1, 32);
  STGA(1, 0, 64); STGB(1, 0, 64);
  __builtin_amdgcn_sched_barrier(0);
  asm volatile("s_waitcnt vmcnt(0)" ::: "memory");
  __builtin_amdgcn_s_barrier();

#pragma unroll
  for (int mm = 0; mm < 4; mm++)
    afrX[mm] = *(const bf16x8*)(&SA[0][0][aoff + mm * 512]);
#pragma unroll
  for (int n = 0; n < 4; n++)
    bfrX[n] = *(const bf16x8*)(&SB[0][0][boff + n * 512]);

  for (int it = 0; it < K / 128; it++) {
    const int t0 = it * 128;
    PH(0, afrX, bfrX, 0, 0, 4, afrY, 0, bfrY, STGA(1, 1, t0 + 96), 0);
    PH(4, afrY, bfrX, 0, 1, 0, afrX, 1, bfrY, STGB(1, 1, t0 + 96), 1);
    PH(0, afrX, bfrY, 0, 1, 4, afrY, 0, bfrX, STGA(0, 0, t0 + 128), 0);
    PH(4, afrY, bfrY, 1, 0, 0, afrX, 1, bfrX, STGB(0, 0, t0 + 128), 1);
    PH(0, afrX, bfrX, 1, 0, 4, afrY, 0, bfrY, STGA(0, 1, t0 + 160), 0);
    PH(4, afrY, bfrX, 1, 1, 0, afrX, 1, bfrY, STGB(0, 1, t0 + 160), 1);
    PH(0, afrX, bfrY, 1, 1, 4, afrY, 0, bfrX, STGA(1, 0, t0 + 192), 0);
    PH(4, afrY, bfrY, 0, 0, 0, afrX, 1, bfrX, STGB(1, 0, t0 + 192), 1);
  }

  const long crow = bm + wm * 128 + g * 4;
  const long ccol = bn + wn * 64 + r16;
  if (BF16_OUT) {
    u16* C = (u16*)Cv;
#pragma unroll
    for (int m = 0; m < 8; m++)
#pragma unroll
      for (int n = 0; n < 4; n++)
#pragma unroll
        for (int j = 0; j < 4; j++)
          C[(crow + m * 16 + j) * (long)N + ccol + n * 16] = f2bf(acc[m][n][j]);
  } else {
    float* C = (float*)Cv;
#pragma unroll
    for (int m = 0; m < 8; m++)
#pragma unroll
      for (int n = 0; n < 4; n++)
#pragma unroll
        for (int j = 0; j < 4; j++)
          C[(crow + m * 16 + j) * (long)N + ccol + n * 16] = acc[m][n][j];
  }
}

// 2D XCD region map (T1): each XCD owns a 4x8 tile rectangle of the 16x16 grid
__device__ __forceinline__ void tile_2d(int bid, long& bm, long& bn) {
  const int xcd = bid & 7, i = bid >> 3;
  bm = (long)((xcd >> 1) * 4 + (i >> 3)) * 256;
  bn = (long)((xcd & 1) * 8 + (i & 7)) * 256;
}

__global__ __launch_bounds__(512, 2) void gemm_q(const u16* __restrict__ A,
                                                 const u16* __restrict__ Bt,
                                                 void* __restrict__ Cv) {
  long bm, bn;
  tile_2d((int)blockIdx.x, bm, bn);
  gemm_core<1>(A, Bt, Cv, bm, bn, 4096, 4096, 4096, 4096);
}

__global__ __launch_bounds__(512, 2) void gemm_kv(const u16* __restrict__ A,
                                                  const u16* __restrict__ Bt,
                                                  u16* __restrict__ part) {
  const int xcd = (int)blockIdx.x & 7, i = (int)blockIdx.x >> 3;
  const int sk = xcd & 1;
  const int rg = xcd >> 1;
  const long bm = (long)(rg * 4 + (i >> 3)) * 256;
  const long bn = (long)(i & 7) * 256;
  gemm_core<1>(A + sk * 2048, Bt + sk * 2048,
               part + (size_t)sk * 4096 * 2048,
               bm, bn, 2048, 2048, 4096, 4096);
}

__global__ __launch_bounds__(512, 2) void gemm_wo(const u16* __restrict__ A,
                                                  const u16* __restrict__ Bt,
                                                  void* __restrict__ Cv) {
  long bm, bn;
  tile_2d((int)blockIdx.x, bm, bn);
  gemm_core<0>(A, Bt, Cv, bm, bn, 4096, 4096, 4096, 4096);
}

// ---------------- causal GQA flash attention (v11: KVBLK=128) ----------------
// v10 structure with 128-kv tiles: rounds 34 -> 17 (nktA+nktB = 17 exactly),
// barriers/staging/shfl-reductions halved, prefetch distance doubled. LDS:
// K 2x32K + V^T 2x32K + P 32K = 160 KB (1 block/CU; R12 measured that
// transition as ~null for this kernel). Index algebra = the proven 64-wide
// mapping applied per 64-kv half (t&3 / kc2>>1 decomposition).
#define ATILE(CUR, I, PREF) do { \
    const int kt_ = ((I) < nktA) ? (I) : (I) - nktA; \
    const int kb_ = kt_ * 128; \
    if (PREF) { \
      const int in_ = (I) + 1; \
      const int ktn_ = (in_ < nktA) ? in_ : in_ - nktA; \
      stage(CUR ^ 1, ktn_ * 128); \
    } \
    if (kb_ <= qlo + 15) { \
      const bool masked_ = (kb_ + 127 > qlo); \
      f32x4 st[8]; \
      _Pragma("unroll") for (int t = 0; t < 8; t++) \
        _Pragma("unroll") for (int j = 0; j < 4; j++) st[t][j] = 0.f; \
      __builtin_amdgcn_s_setprio(1); \
      _Pragma("unroll") for (int t = 0; t < 8; t++) \
        _Pragma("unroll") for (int kc = 0; kc < 4; kc++) { \
          bf16x8 kf = *(const bf16x8*)(kaK[CUR][kc & 1] + t * 2048 + (kc >> 1) * 64); \
          st[t] = __builtin_amdgcn_mfma_f32_16x16x32_bf16(kf, qf[kc], st[t], 0, 0, 0); \
        } \
      __builtin_amdgcn_s_setprio(0); \
      float p[8][4]; \
      float ps0 = 0.f, ps1 = 0.f; \
      _Pragma("unroll") for (int t = 0; t < 8; t++) \
        _Pragma("unroll") for (int j = 0; j < 4; j++) { \
          float s = st[t][j]; \
          if (masked_) { \
            int kv = kb_ + t * 16 + g * 4 + j; \
            s = (kv > qrow) ? -__builtin_inff() : s; \
          } \
          float e = exp2f(s); \
          p[t][j] = e; \
          if (t < 4) ps0 += e; else ps1 += e; \
        } \
      float psum = ps0 + ps1; \
      psum += __shfl_xor(psum, 16); \
      psum += __shfl_xor(psum, 32); \
      lrun += psum; \
      _Pragma("unroll") for (int t = 0; t < 8; t++) \
        _Pragma("unroll") for (int pp = 0; pp < 2; pp++) \
          *pwp32[t * 2 + pp] = cvt_pk_bf16(p[t][pp * 2], p[t][pp * 2 + 1]); \
      _Pragma("unroll") for (int kc2 = 0; kc2 < 4; kc2++) { \
        bf16x8 pa = *(const bf16x8*)(paP[kc2]); \
        __builtin_amdgcn_s_setprio(1); \
        _Pragma("unroll") for (int dt = 0; dt < 8; dt++) { \
          bf16x8 vf = *(const bf16x8*)(vaV[CUR][kc2 & 1] + dt * 2048 + (kc2 >> 1) * 64); \
          oacc[dt] = __builtin_amdgcn_mfma_f32_16x16x32_bf16(pa, vf, oacc[dt], 0, 0, 0); \
        } \
        __builtin_amdgcn_s_setprio(0); \
      } \
    } \
    __syncthreads(); \
  } while (0)

#define SWITCHQ { \
    finalize(); \
    qbase = qtB * 128; \
    qlo = qbase + w * 16; \
    qrow = qlo + r16; \
    load_q(); \
    reinit(); \
  }

__global__ __launch_bounds__(512) void attn_fwd(const u16* __restrict__ Q,
                                                const u16* __restrict__ KV,
                                                const u16* __restrict__ VT,
                                                u16* __restrict__ Og) {
  __shared__ u16 Ks[2][128 * 128];
  __shared__ u16 Vs[2][128 * 128];
  __shared__ u16 Ps[8][16 * 128];
  const int tid = threadIdx.x;
  const int lane = tid & 63;
  const int w = tid >> 6;
  const int g = lane >> 4, r16 = lane & 15;

  const int lin = ((int)blockIdx.x & 7) * 64 + ((int)blockIdx.x >> 3);
  const int b = lin >> 8;
  const int rem = lin & 255;
  const int kvh = rem >> 5;
  const int hrep = (rem & 31) >> 3;
  const int qtA = rem & 7;
  const int qtB = 15 - qtA;
  const int h = kvh * 4 + hrep;

  const u16* kcol   = KV + (long)b * 2048 * 2048 + kvh * 128;
  const u16* vb_ptr = VT + (long)kvh * 128 * 4096 + (long)b * 2048;
  u16* pw = Ps[w];

  const int nktA = qtA + 1;     // 128-kv tiles for Q-tile A; total = 17 always

  int qbase = qtA * 128;
  int qlo = qbase + w * 16;
  int qrow = qlo + r16;

  // ---- hoisted LDS pointers (loop-invariant; static indices only) ----
  const int swz = r16 & 7;
  const u16* kaK[2][2];
  const u16* vaV[2][2];
  const u16* paP[4];
  unsigned* pwp32[16];
#pragma unroll
  for (int c2 = 0; c2 < 2; c2++) {
#pragma unroll
    for (int v = 0; v < 2; v++) {
      kaK[c2][v] = &Ks[c2][r16 * 128 + ((swz ^ (g + v * 4)) * 8)];
      vaV[c2][v] = &Vs[c2][r16 * 128 + ((swz ^ (v * 4 + g)) * 8)];
    }
  }
#pragma unroll
  for (int kc2 = 0; kc2 < 4; kc2++)
    paP[kc2] = pw + r16 * 128 + (kc2 >> 1) * 64 + ((swz ^ ((kc2 & 1) * 4 + g)) * 8);
#pragma unroll
  for (int t = 0; t < 8; t++)
#pragma unroll
    for (int pp = 0; pp < 2; pp++)
      pwp32[t * 2 + pp] = (unsigned*)((char*)pw + r16 * 256 + (t >> 2) * 128 +
                          ((((t & 3) * 32 + g * 8 + pp * 4) ^ (swz << 4))));

  bf16x8 qf[4];
  auto load_q = [&]() {
    const u16* qp = Q + ((long)(b * 2048 + qrow)) * 4096 + h * 128 + g * 8;
#pragma unroll
    for (int kc = 0; kc < 4; kc++) qf[kc] = *(const bf16x8*)(qp + kc * 32);
  };
  load_q();

  f32x4 oacc[8];
  float lrun;
  auto reinit = [&]() {
#pragma unroll
    for (int dt = 0; dt < 8; dt++)
#pragma unroll
      for (int j = 0; j < 4; j++) oacc[dt][j] = 0.f;
    lrun = 0.f;
  };
  reinit();

  auto finalize = [&]() {
    float li[4];
#pragma unroll
    for (int j = 0; j < 4; j++)
      li[j] = 1.f / __shfl(lrun, (lane & 48) + g * 4 + j);
    u16* op = Og + ((long)(b * 2048 + qbase + w * 16 + g * 4)) * 4096 + h * 128 + r16;
#pragma unroll
    for (int dt = 0; dt < 8; dt++)
#pragma unroll
      for (int j = 0; j < 4; j++)
        op[(long)j * 4096 + dt * 16] = f2bf(oacc[dt][j] * li[j]);
  };

  // stage 128-kv tile: K [128][128] + V^T [128][128], 4 slots each per thread
  auto stage = [&](int bf, int kb) {
#pragma unroll
    for (int i = 0; i < 4; i++) {
      int slot = i * 512 + tid;
      int r = slot >> 4, cs = slot & 15;
      int ck = (cs & 8) | ((cs ^ r) & 7);
      load_lds16(kcol + (long)(kb + r) * 2048 + ck * 8, &Ks[bf][slot * 8]);
      int cv = (cs & 8) | ((cs ^ r) & 7);
      load_lds16(vb_ptr + (long)r * 4096 + kb + cv * 8, &Vs[bf][slot * 8]);
    }
  };

  stage(0, 0);
  __syncthreads();

  for (int i = 0; i < 17; i += 2) {
    if (i == nktA) SWITCHQ;
    ATILE(0, i, (i + 1 < 17));
    if (i + 1 < 17) {
      if (i + 1 == nktA) SWITCHQ;
      ATILE(1, i + 1, (i + 2 < 17));
    }
  }

  finalize();
}

// ---------------- launch ----------------
extern "C" void kernel_launch(void* const* d_in, const int* in_sizes, int n_in,
                              void* d_out, int out_size, void* d_ws, size_t ws_size,
                              hipStream_t stream) {
  (void)in_sizes; (void)n_in; (void)out_size; (void)ws_size;
  const float* x  = (const float*)d_in[0];
  const float* wq = (const float*)d_in[1];
  const float* wk = (const float*)d_in[2];
  const float* wv = (const float*)d_in[3];
  const float* wo = (const float*)d_in[4];
  float* out = (float*)d_out;

  u16* xb    = (u16*)d_ws;                          // 4096x4096 bf16 (x); reused as attn out
  u16* wqT   = xb   + (size_t)4096 * 4096;          // 4096x4096 (N,K), pre-scaled
  u16* wkvT  = wqT  + (size_t)4096 * 4096;          // 2048x4096: wkT | wvT
  u16* woT   = wkvT + (size_t)2048 * 4096;          // 4096x4096
  u16* qb    = woT  + (size_t)4096 * 4096;          // 4096x4096 Q
  u16* kvb   = qb   + (size_t)4096 * 4096;          // 4096x2048: K | V (V-half unused)
  u16* vT    = kvb  + (size_t)4096 * 2048;          // 1024x4096 V^T
  u16* attn  = xb;                                  // xb dead after projections
  u16* partu = (u16*)out;                           // 2x bf16[4096][2048] partials

  prep_all<<<22528, 256, 0, stream>>>(x, wq, wk, wv, wo, xb, wqT, wkvT, woT);

  gemm_q<<<256, 512, 0, stream>>>(xb, wqT, qb);
  gemm_kv<<<256, 512, 0, stream>>>(xb, wkvT, partu);
  reduce_tr<<<dim3(32, 128), 256, 0, stream>>>(partu, kvb, vT);

  attn_fwd<<<512, 512, 0, stream>>>(qb, kvb, vT, attn);

  gemm_wo<<<256, 512, 0, stream>>>(attn, woT, out);
}

// Round 27
// 474.165 us; speedup vs baseline: 1.0661x; 1.0661x over previous
//
#include <hip/hip_runtime.h>
#include <cstdint>
#include <cstddef>

typedef __bf16 bf16x8 __attribute__((ext_vector_type(8)));
typedef float  f32x4  __attribute__((ext_vector_type(4)));
typedef unsigned short u16;

#define SCALE_F 0.08838834764831845f
#define QSCALE_F (0.08838834764831845f * 1.4426950408889634f)  // SCALE * log2(e)

__device__ __forceinline__ u16 f2bf(float f) {
  unsigned int u = __builtin_bit_cast(unsigned int, f);
  u += 0x7fffu + ((u >> 16) & 1u);
  return (u16)(u >> 16);
}

__device__ __forceinline__ float b2f(u16 v) {
  unsigned u = (unsigned)v << 16;
  return __builtin_bit_cast(float, u);
}

__device__ __forceinline__ unsigned cvt_pk_bf16(float lo, float hi) {
  unsigned r;
  asm("v_cvt_pk_bf16_f32 %0, %1, %2" : "=v"(r) : "v"(lo), "v"(hi));
  return r;
}

__device__ __forceinline__ void load_lds16(const void* g, void* l) {
  __builtin_amdgcn_global_load_lds((const __attribute__((address_space(1))) void*)g,
                                   (__attribute__((address_space(3))) void*)l,
                                   16, 0, 0);
}

// ------------- fused prep: x cast + weight transposes (64x32 tiles) ----------
__global__ __launch_bounds__(256) void prep_all(const float* __restrict__ x,
                                                const float* __restrict__ wq,
                                                const float* __restrict__ wk,
                                                const float* __restrict__ wv,
                                                const float* __restrict__ wo,
                                                u16* __restrict__ xb,
                                                u16* __restrict__ wqT,
                                                u16* __restrict__ wkvT,
                                                u16* __restrict__ woT) {
  __shared__ float tile[64][33];
  const int tid = threadIdx.x;
  int blk = blockIdx.x;
  if (blk < 2048) {
    int idx = blk * 256 + tid;
    const int n4 = 4096 * 4096 / 4;
    for (; idx < n4; idx += 2048 * 256) {
      float4 v = ((const float4*)x)[idx];
      uint2 pk;
      pk.x = (unsigned)f2bf(v.x) | ((unsigned)f2bf(v.y) << 16);
      pk.y = (unsigned)f2bf(v.z) | ((unsigned)f2bf(v.w) << 16);
      ((uint2*)xb)[idx] = pk;
    }
    return;
  }
  blk -= 2048;
  const float* in; u16* out; long C; int nbx; float scale;
  if (blk < 8192)       { in = wq; out = wqT;                           C = 4096; nbx = 128; scale = QSCALE_F; }
  else if (blk < 10240) { blk -= 8192;  in = wk; out = wkvT;                          C = 1024; nbx = 32; scale = 1.f; }
  else if (blk < 12288) { blk -= 10240; in = wv; out = wkvT + (size_t)1024 * 4096;    C = 1024; nbx = 32; scale = 1.f; }
  else                  { blk -= 12288; in = wo; out = woT;                           C = 4096; nbx = 128; scale = 1.f; }
  const long R = 4096;
  const long c0 = (long)(blk % nbx) * 32, r0 = (long)(blk / nbx) * 64;
  {
    const int tx = tid & 31, ty = tid >> 5;
#pragma unroll
    for (int i = 0; i < 8; i++)
      tile[ty + i * 8][tx] = in[(r0 + ty + i * 8) * C + c0 + tx];
  }
  __syncthreads();
  {
    const int tx = tid & 31, cy = tid >> 5;
#pragma unroll
    for (int i = 0; i < 4; i++) {
      int col = cy + i * 8;
      unsigned val = (unsigned)f2bf(tile[2 * tx][col] * scale) |
                     ((unsigned)f2bf(tile[2 * tx + 1][col] * scale) << 16);
      *(unsigned*)&out[(c0 + col) * R + r0 + 2 * tx] = val;
    }
  }
}

// ---- fused split-K reduce + V transpose over bf16 partials ------------------
__global__ __launch_bounds__(256) void reduce_tr(const u16* __restrict__ part,
                                                 u16* __restrict__ kvb,
                                                 u16* __restrict__ vT) {
  __shared__ u16 tile[64][33];
  const u16* p0 = part;
  const u16* p1 = part + (size_t)4096 * 2048;
  const int tx = threadIdx.x & 31, ty = threadIdx.x >> 5;
  const long c0 = (long)blockIdx.x * 64;   // 0..2047 step 64
  const long r0 = (long)blockIdx.y * 32;
  if (c0 < 1024) {
#pragma unroll
    for (int i = 0; i < 4; i++) {
      const long r = r0 + ty + i * 8;
      unsigned a = *(const unsigned*)&p0[r * 2048 + c0 + 2 * tx];
      unsigned b = *(const unsigned*)&p1[r * 2048 + c0 + 2 * tx];
      unsigned v = (unsigned)f2bf(b2f((u16)a) + b2f((u16)b)) |
                   ((unsigned)f2bf(b2f((u16)(a >> 16)) + b2f((u16)(b >> 16))) << 16);
      *(unsigned*)&kvb[r * 2048 + c0 + 2 * tx] = v;
    }
  } else {
#pragma unroll
    for (int i = 0; i < 4; i++) {
      const long r = r0 + ty + i * 8;
      unsigned a = *(const unsigned*)&p0[r * 2048 + c0 + 2 * tx];
      unsigned b = *(const unsigned*)&p1[r * 2048 + c0 + 2 * tx];
      tile[2 * tx][ty + i * 8]     = f2bf(b2f((u16)a) + b2f((u16)b));
      tile[2 * tx + 1][ty + i * 8] = f2bf(b2f((u16)(a >> 16)) + b2f((u16)(b >> 16)));
    }
    __syncthreads();
    const long d0 = c0 - 1024;
#pragma unroll
    for (int i = 0; i < 8; i++)
      vT[(d0 + ty + i * 8) * 4096 + r0 + tx] = tile[ty + i * 8][tx];
  }
}

// ------------- 256x256 8-phase bf16 GEMM core (R9 de-walled schedule) --------
#define STGA(db, ks, KC) { int kc_ = (KC) < K ? (KC) : 0; \
    load_lds16(gA0 + kc_, &SA[db][ks][s0 * 8]); \
    load_lds16(gA1 + kc_, &SA[db][ks][s1 * 8]); }
#define STGB(db, ks, KC) { int kc_ = (KC) < K ? (KC) : 0; \
    load_lds16(gB0 + kc_, &SB[db][ks][s0 * 8]); \
    load_lds16(gB1 + kc_, &SB[db][ks][s1 * 8]); }

#define PH(MBc, AU, BU, DBn, KSn, MBn, AN, RDB, BN_, STG, DOVM) { \
    STG; \
    if (DOVM) asm volatile("s_waitcnt vmcnt(8)"); \
    __builtin_amdgcn_s_barrier(); \
    _Pragma("unroll") for (int mm = 0; mm < 4; mm++) \
      AN[mm] = *(const bf16x8*)(&SA[DBn][KSn][aoff + (MBn + mm) * 512]); \
    if (RDB) { \
      _Pragma("unroll") for (int n = 0; n < 4; n++) \
        BN_[n] = *(const bf16x8*)(&SB[DBn][KSn][boff + n * 512]); \
    } \
    __builtin_amdgcn_s_setprio(1); \
    _Pragma("unroll") for (int mm = 0; mm < 4; mm++) \
      _Pragma("unroll") for (int n = 0; n < 4; n++) \
        acc[MBc + mm][n] = __builtin_amdgcn_mfma_f32_16x16x32_bf16(AU[mm], BU[n], acc[MBc + mm][n], 0, 0, 0); \
    __builtin_amdgcn_s_setprio(0); \
  }

template <int BF16_OUT>
__device__ __forceinline__ void gemm_core(const u16* __restrict__ A,
                                          const u16* __restrict__ Bt,
                                          void* __restrict__ Cv,
                                          long bm, long bn,
                                          int N, int K, int lda, int ldb) {
  __shared__ u16 SA[2][2][8192];
  __shared__ u16 SB[2][2][8192];
  const int tid = threadIdx.x;
  const int lane = tid & 63;
  const int g = lane >> 4, r16 = lane & 15;
  const int wid = tid >> 6;
  const int wm = wid >> 2, wn = wid & 3;

  const int s0 = tid, s1 = 512 + tid;
  const int rp0 = s0 >> 3, ci0 = (s0 & 7) ^ (rp0 & 7);
  const int rp1 = s1 >> 3, ci1 = (s1 & 7) ^ (rp1 & 7);
  const long gr0 = rp0 * 2 + (ci0 >> 2), gc0 = (ci0 & 3) * 8;
  const long gr1 = rp1 * 2 + (ci1 >> 2), gc1 = (ci1 & 3) * 8;
  const u16* gA0 = A + (bm + gr0) * lda + gc0;
  const u16* gA1 = A + (bm + gr1) * lda + gc1;
  const u16* gB0 = Bt + (bn + gr0) * ldb + gc0;
  const u16* gB1 = Bt + (bn + gr1) * ldb + gc1;

  const int rA = wm * 128 + r16;
  const int aoff = (rA >> 1) * 64 + ((((rA & 1) << 2) + g) ^ ((rA >> 1) & 7)) * 8;
  const int rB = wn * 64 + r16;
  const int boff = (rB >> 1) * 64 + ((((rB & 1) << 2) + g) ^ ((rB >> 1) & 7)) * 8;

  f32x4 acc[8][4];
#pragma unroll
  for (int m = 0; m < 8; m++)
#pragma unroll
    for (int n = 0; n < 4; n++)
#pragma unroll
      for (int j = 0; j < 4; j++) acc[m][n][j] = 0.f;

  bf16x8 afrX[4], afrY[4], bfrX[4], bfrY[4];

  STGA(0, 0, 0); STGB(0, 0, 0);
  STGA(0, 1, 32); STGB(0, 1, 32);
  STGA(1, 0, 64); STGB(1, 0, 64);
  __builtin_amdgcn_sched_barrier(0);
  asm volatile("s_waitcnt vmcnt(0)" ::: "memory");
  __builtin_amdgcn_s_barrier();

#pragma unroll
  for (int mm = 0; mm < 4; mm++)
    afrX[mm] = *(const bf16x8*)(&SA[0][0][aoff + mm * 512]);
#pragma unroll
  for (int n = 0; n < 4; n++)
    bfrX[n] = *(const bf16x8*)(&SB[0][0][boff + n * 512]);

  for (int it = 0; it < K / 128; it++) {
    const int t0 = it * 128;
    PH(0, afrX, bfrX, 0, 0, 4, afrY, 0, bfrY, STGA(1, 1, t0 + 96), 0);
    PH(4, afrY, bfrX, 0, 1, 0, afrX, 1, bfrY, STGB(1, 1, t0 + 96), 1);
    PH(0, afrX, bfrY, 0, 1, 4, afrY, 0, bfrX, STGA(0, 0, t0 + 128), 0);
    PH(4, afrY, bfrY, 1, 0, 0, afrX, 1, bfrX, STGB(0, 0, t0 + 128), 1);
    PH(0, afrX, bfrX, 1, 0, 4, afrY, 0, bfrY, STGA(0, 1, t0 + 160), 0);
    PH(4, afrY, bfrX, 1, 1, 0, afrX, 1, bfrY, STGB(0, 1, t0 + 160), 1);
    PH(0, afrX, bfrY, 1, 1, 4, afrY, 0, bfrX, STGA(1, 0, t0 + 192), 0);
    PH(4, afrY, bfrY, 0, 0, 0, afrX, 1, bfrX, STGB(1, 0, t0 + 192), 1);
  }

  const long crow = bm + wm * 128 + g * 4;
  const long ccol = bn + wn * 64 + r16;
  if (BF16_OUT) {
    u16* C = (u16*)Cv;
#pragma unroll
    for (int m = 0; m < 8; m++)
#pragma unroll
      for (int n = 0; n < 4; n++)
#pragma unroll
        for (int j = 0; j < 4; j++)
          C[(crow + m * 16 + j) * (long)N + ccol + n * 16] = f2bf(acc[m][n][j]);
  } else {
    float* C = (float*)Cv;
#pragma unroll
    for (int m = 0; m < 8; m++)
#pragma unroll
      for (int n = 0; n < 4; n++)
#pragma unroll
        for (int j = 0; j < 4; j++)
          C[(crow + m * 16 + j) * (long)N + ccol + n * 16] = acc[m][n][j];
  }
}

// 2D XCD region map (T1): each XCD owns a 4x8 tile rectangle of the 16x16 grid
__device__ __forceinline__ void tile_2d(int bid, long& bm, long& bn) {
  const int xcd = bid & 7, i = bid >> 3;
  bm = (long)((xcd >> 1) * 4 + (i >> 3)) * 256;
  bn = (long)((xcd & 1) * 8 + (i & 7)) * 256;
}

__global__ __launch_bounds__(512, 2) void gemm_q(const u16* __restrict__ A,
                                                 const u16* __restrict__ Bt,
                                                 void* __restrict__ Cv) {
  long bm, bn;
  tile_2d((int)blockIdx.x, bm, bn);
  gemm_core<1>(A, Bt, Cv, bm, bn, 4096, 4096, 4096, 4096);
}

__global__ __launch_bounds__(512, 2) void gemm_kv(const u16* __restrict__ A,
                                                  const u16* __restrict__ Bt,
                                                  u16* __restrict__ part) {
  const int xcd = (int)blockIdx.x & 7, i = (int)blockIdx.x >> 3;
  const int sk = xcd & 1;
  const int rg = xcd >> 1;
  const long bm = (long)(rg * 4 + (i >> 3)) * 256;
  const long bn = (long)(i & 7) * 256;
  gemm_core<1>(A + sk * 2048, Bt + sk * 2048,
               part + (size_t)sk * 4096 * 2048,
               bm, bn, 2048, 2048, 4096, 4096);
}

__global__ __launch_bounds__(512, 2) void gemm_wo(const u16* __restrict__ A,
                                                  const u16* __restrict__ Bt,
                                                  void* __restrict__ Cv) {
  long bm, bn;
  tile_2d((int)blockIdx.x, bm, bn);
  gemm_core<0>(A, Bt, Cv, bm, bn, 4096, 4096, 4096, 4096);
}

// ---------------- causal GQA flash attention (v10: fixed-max, R25 exact) -----
#define ATILE(CUR, I, PREF) do { \
    const int kt_ = ((I) < nktA) ? (I) : (I) - nktA; \
    const int kb_ = kt_ * 64; \
    if (PREF) { \
      const int in_ = (I) + 1; \
      const int ktn_ = (in_ < nktA) ? in_ : in_ - nktA; \
      stage(CUR ^ 1, ktn_ * 64); \
    } \
    if (kb_ <= qlo + 15) { \
      const bool masked_ = (kb_ + 63 > qlo); \
      f32x4 st[4]; \
      _Pragma("unroll") for (int t = 0; t < 4; t++) \
        _Pragma("unroll") for (int j = 0; j < 4; j++) st[t][j] = 0.f; \
      __builtin_amdgcn_s_setprio(1); \
      _Pragma("unroll") for (int t = 0; t < 4; t++) \
        _Pragma("unroll") for (int kc = 0; kc < 4; kc++) { \
          bf16x8 kf = *(const bf16x8*)(kaK[CUR][kc & 1] + t * 2048 + (kc >> 1) * 64); \
          st[t] = __builtin_amdgcn_mfma_f32_16x16x32_bf16(kf, qf[kc], st[t], 0, 0, 0); \
        } \
      __builtin_amdgcn_s_setprio(0); \
      float p[4][4]; \
      float ps01 = 0.f, ps23 = 0.f; \
      _Pragma("unroll") for (int t = 0; t < 4; t++) \
        _Pragma("unroll") for (int j = 0; j < 4; j++) { \
          float s = st[t][j]; \
          if (masked_) { \
            int kv = kb_ + t * 16 + g * 4 + j; \
            s = (kv > qrow) ? -__builtin_inff() : s; \
          } \
          float e = exp2f(s); \
          p[t][j] = e; \
          if (t < 2) ps01 += e; else ps23 += e; \
        } \
      float psum = ps01 + ps23; \
      psum += __shfl_xor(psum, 16); \
      psum += __shfl_xor(psum, 32); \
      lrun += psum; \
      _Pragma("unroll") for (int t = 0; t < 4; t++) \
        _Pragma("unroll") for (int pp = 0; pp < 2; pp++) \
          *pwp32[t * 2 + pp] = cvt_pk_bf16(p[t][pp * 2], p[t][pp * 2 + 1]); \
      _Pragma("unroll") for (int kc2 = 0; kc2 < 2; kc2++) { \
        bf16x8 pa = *(const bf16x8*)(paP[kc2]); \
        __builtin_amdgcn_s_setprio(1); \
        _Pragma("unroll") for (int dt = 0; dt < 8; dt++) { \
          bf16x8 vf = *(const bf16x8*)(vaV[CUR][kc2] + dt * 1024); \
          oacc[dt] = __builtin_amdgcn_mfma_f32_16x16x32_bf16(pa, vf, oacc[dt], 0, 0, 0); \
        } \
        __builtin_amdgcn_s_setprio(0); \
      } \
    } \
    __syncthreads(); \
  } while (0)

__global__ __launch_bounds__(512, 4) void attn_fwd(const u16* __restrict__ Q,
                                                   const u16* __restrict__ KV,
                                                   const u16* __restrict__ VT,
                                                   u16* __restrict__ Og) {
  __shared__ u16 Ks[2][64 * 128];
  __shared__ u16 Vs[2][128 * 64];
  __shared__ u16 Ps[8][16 * 64];
  const int tid = threadIdx.x;
  const int lane = tid & 63;
  const int w = tid >> 6;
  const int g = lane >> 4, r16 = lane & 15;

  const int lin = ((int)blockIdx.x & 7) * 64 + ((int)blockIdx.x >> 3);
  const int b = lin >> 8;
  const int rem = lin & 255;
  const int kvh = rem >> 5;
  const int hrep = (rem & 31) >> 3;
  const int qtA = rem & 7;
  const int qtB = 15 - qtA;
  const int h = kvh * 4 + hrep;

  const u16* kcol   = KV + (long)b * 2048 * 2048 + kvh * 128;
  const u16* vb_ptr = VT + (long)kvh * 128 * 4096 + (long)b * 2048;
  u16* pw = Ps[w];

  const int nktA = 2 * (qtA + 1);
  const int ntot = 34;

  int qbase = qtA * 128;
  int qlo = qbase + w * 16;
  int qrow = qlo + r16;

  // ---- hoisted LDS pointers (loop-invariant; static indices only) ----
  const int swz = r16 & 7;
  const u16* kaK[2][2];
  const u16* vaV[2][2];
  const u16* paP[2];
  unsigned* pwp32[8];
#pragma unroll
  for (int c2 = 0; c2 < 2; c2++) {
#pragma unroll
    for (int v = 0; v < 2; v++) {
      kaK[c2][v] = &Ks[c2][r16 * 128 + ((swz ^ (g + v * 4)) * 8)];
      vaV[c2][v] = &Vs[c2][r16 * 64 + ((swz ^ (v * 4 + g)) * 8)];
    }
  }
#pragma unroll
  for (int v = 0; v < 2; v++)
    paP[v] = pw + r16 * 64 + ((swz ^ (v * 4 + g)) * 8);
#pragma unroll
  for (int t = 0; t < 4; t++)
#pragma unroll
    for (int pp = 0; pp < 2; pp++)
      pwp32[t * 2 + pp] = (unsigned*)((char*)pw + r16 * 128 +
                          (((t * 32 + g * 8 + pp * 4) ^ (swz << 4))));

  bf16x8 qf[4];
  auto load_q = [&]() {
    const u16* qp = Q + ((long)(b * 2048 + qrow)) * 4096 + h * 128 + g * 8;
#pragma unroll
    for (int kc = 0; kc < 4; kc++) qf[kc] = *(const bf16x8*)(qp + kc * 32);
  };
  load_q();

  f32x4 oacc[8];
  float lrun;
  auto reinit = [&]() {
#pragma unroll
    for (int dt = 0; dt < 8; dt++)
#pragma unroll
      for (int j = 0; j < 4; j++) oacc[dt][j] = 0.f;
    lrun = 0.f;
  };
  reinit();

  auto finalize = [&]() {
    float li[4];
#pragma unroll
    for (int j = 0; j < 4; j++)
      li[j] = 1.f / __shfl(lrun, (lane & 48) + g * 4 + j);
    u16* op = Og + ((long)(b * 2048 + qbase + w * 16 + g * 4)) * 4096 + h * 128 + r16;
#pragma unroll
    for (int dt = 0; dt < 8; dt++)
#pragma unroll
      for (int j = 0; j < 4; j++)
        op[(long)j * 4096 + dt * 16] = f2bf(oacc[dt][j] * li[j]);
  };

  auto stage = [&](int bf, int kb) {
#pragma unroll
    for (int i = 0; i < 2; i++) {
      int slot = i * 512 + tid;
      int r = slot >> 4, cs = slot & 15;
      int ck = (cs & 8) | ((cs ^ r) & 7);
      load_lds16(kcol + (long)(kb + r) * 2048 + ck * 8, &Ks[bf][slot * 8]);
      int d = slot >> 3, c8 = slot & 7;
      int cv = (c8 ^ d) & 7;
      load_lds16(vb_ptr + (long)d * 4096 + kb + cv * 8, &Vs[bf][slot * 8]);
    }
  };

  stage(0, 0);
  __syncthreads();

  for (int i = 0; i < ntot; i += 2) {
    if (i == nktA) {  // block-uniform; nktA is always even
      finalize();
      qbase = qtB * 128;
      qlo = qbase + w * 16;
      qrow = qlo + r16;
      load_q();
      reinit();
    }
    ATILE(0, i, 1);
    ATILE(1, i + 1, (i + 2 < ntot));
  }

  finalize();
}

// ---------------- launch ----------------
extern "C" void kernel_launch(void* const* d_in, const int* in_sizes, int n_in,
                              void* d_out, int out_size, void* d_ws, size_t ws_size,
                              hipStream_t stream) {
  (void)in_sizes; (void)n_in; (void)out_size; (void)ws_size;
  const float* x  = (const float*)d_in[0];
  const float* wq = (const float*)d_in[1];
  const float* wk = (const float*)d_in[2];
  const float* wv = (const float*)d_in[3];
  const float* wo = (const float*)d_in[4];
  float* out = (float*)d_out;

  u16* xb    = (u16*)d_ws;                          // 4096x4096 bf16 (x); reused as attn out
  u16* wqT   = xb   + (size_t)4096 * 4096;          // 4096x4096 (N,K), pre-scaled
  u16* wkvT  = wqT  + (size_t)4096 * 4096;          // 2048x4096: wkT | wvT
  u16* woT   = wkvT + (size_t)2048 * 4096;          // 4096x4096
  u16* qb    = woT  + (size_t)4096 * 4096;          // 4096x4096 Q
  u16* kvb   = qb   + (size_t)4096 * 4096;          // 4096x2048: K | V (V-half unused)
  u16* vT    = kvb  + (size_t)4096 * 2048;          // 1024x4096 V^T
  u16* attn  = xb;                                  // xb dead after projections
  u16* partu = (u16*)out;                           // 2x bf16[4096][2048] partials

  prep_all<<<22528, 256, 0, stream>>>(x, wq, wk, wv, wo, xb, wqT, wkvT, woT);

  gemm_q<<<256, 512, 0, stream>>>(xb, wqT, qb);
  gemm_kv<<<256, 512, 0, stream>>>(xb, wkvT, partu);
  reduce_tr<<<dim3(32, 128), 256, 0, stream>>>(partu, kvb, vT);

  attn_fwd<<<512, 512, 0, stream>>>(qb, kvb, vT, attn);

  gemm_wo<<<256, 512, 0, stream>>>(attn, woT, out);
}